// Round 10
// baseline (130.697 us; speedup 1.0000x reference)
//
#include <hip/hip_runtime.h>
#include <math.h>

#define N_ROWS 16384
#define DIM 4096
#define NEXP 64
#define KWAVES 8
#define KSLICE (DIM / KWAVES)      // 512 k per wave
#define NK16 (KSLICE / 16)         // 32 K-steps of 16 per wave
#define RPB 32                     // rows per block = one 32x32 MFMA M-tile
#define NSTEP (DIM / 16)           // 256 global K-steps

typedef short short8 __attribute__((ext_vector_type(8)));
typedef float f32x16 __attribute__((ext_vector_type(16)));

__device__ __forceinline__ unsigned cvt_pk_bf16(float a, float b) {
    unsigned r;
    asm("v_cvt_pk_bf16_f32 %0, %1, %2" : "=v"(r) : "v"(a), "v"(b));
    return r;   // low16 = bf16(a), high16 = bf16(b)
}

// 3-way split of 8 f32 into bf16 hi/mid/lo frags; residuals exact (<= 2^-27 |x|).
__device__ __forceinline__ void split3(const float* xv, short8& h8, short8& m8, short8& l8) {
    union { unsigned u[4]; short8 s; } H, M, L;
#pragma unroll
    for (int j = 0; j < 4; ++j) {
        float a = xv[2 * j], b = xv[2 * j + 1];
        unsigned hp = cvt_pk_bf16(a, b);
        float a1 = a - __uint_as_float(hp << 16);
        float b1 = b - __uint_as_float(hp & 0xffff0000u);
        unsigned mp = cvt_pk_bf16(a1, b1);
        float a2 = a1 - __uint_as_float(mp << 16);
        float b2 = b1 - __uint_as_float(mp & 0xffff0000u);
        H.u[j] = hp; M.u[j] = mp; L.u[j] = cvt_pk_bf16(a2, b2);
    }
    h8 = H.s; m8 = M.s; l8 = L.s;
}

__device__ __forceinline__ bool gtpair(float a, int ia, float b, int ib) {
    return (a > b) || (a == b && ia < ib);
}

// ---- pre-kernel: W[64][4096] f32 -> 3 bf16 tables, layout idx = (s*2+nt)*64+l,
// e = nt*32 + (l&31), k = s*16 + (l>>5)*8 (matches 32x32 B-frag lane mapping) ----
__global__ __launch_bounds__(256)
void convw_kernel(const float* __restrict__ w, short8* __restrict__ w0t,
                  short8* __restrict__ w1t, short8* __restrict__ w2t)
{
    const int t  = blockIdx.x * 256 + threadIdx.x;   // 32768 = 256 s x 2 nt x 64 l
    const int s  = t >> 7;
    const int nt = (t >> 6) & 1;
    const int l  = t & 63;
    const int e  = nt * 32 + (l & 31);
    const int k  = s * 16 + (l >> 5) * 8;
    const float* src = w + (size_t)e * DIM + k;
    float xv[8];
#pragma unroll
    for (int j = 0; j < 8; ++j) xv[j] = src[j];
    short8 h, m, lo;
    split3(xv, h, m, lo);
    w0t[t] = h; w1t[t] = m; w2t[t] = lo;
}

#define MFMA32(A, B, C) __builtin_amdgcn_mfma_f32_32x32x16_bf16((A), (B), (C), 0, 0, 0)

// ---- main: 512 blocks x 8 waves; wave wv covers k-slice [wv*512, wv*512+512)
// for the block's 32 rows (single 32x32 M-tile). A: row = lane&31, k-octet =
// lane>>5 (A/B share k-order => consistent). C (m74/m101-verified):
// col = lane&31, row = (reg&3) + 8*(reg>>2) + 4*(lane>>5).
__global__ __launch_bounds__(512, 4)
void gate_kernel(const float* __restrict__ x, const short8* __restrict__ w0t,
                 const short8* __restrict__ w1t, const short8* __restrict__ w2t,
                 float* __restrict__ out)
{
    __shared__ float part[KWAVES][RPB][NEXP];   // 64 KB

    const int tid  = threadIdx.x;
    const int lane = tid & 63;
    const int wv   = tid >> 6;                  // 0..7 = k-slice
    const int e31  = lane & 31;
    const int h    = lane >> 5;
    const int row0 = blockIdx.x * RPB;

    f32x16 acc0, acc1;
#pragma unroll
    for (int j = 0; j < 16; ++j) { acc0[j] = 0.f; acc1[j] = 0.f; }

    const float* xp = x + (size_t)(row0 + e31) * DIM + wv * KSLICE + h * 8;

    short8 wA0, wA1, wA2, wA3, wA4, wA5;        // step-A W frags (b0/b1/b2 x nt0/nt1)
    short8 wB0, wB1, wB2, wB3, wB4, wB5;
    float4 xA0, xA1, xB0, xB1;

#define LOADW(p0, p1, p2, p3, p4, p5, S)                                       \
    do {                                                                       \
        const int _i = ((wv * NK16 + (S)) * 2) * 64 + lane;                    \
        p0 = w0t[_i];      p1 = w1t[_i];      p2 = w2t[_i];                    \
        p3 = w0t[_i + 64]; p4 = w1t[_i + 64]; p5 = w2t[_i + 64];               \
    } while (0)

#define LOADX(d0, d1, S)                                                       \
    do {                                                                       \
        d0 = *reinterpret_cast<const float4*>(xp + (S) * 16);                  \
        d1 = *reinterpret_cast<const float4*>(xp + (S) * 16 + 4);              \
    } while (0)

#define DOSTEP(X0, X1, q0, q1, q2, q3, q4, q5)                                 \
    do {                                                                       \
        float xv[8] = {X0.x, X0.y, X0.z, X0.w, X1.x, X1.y, X1.z, X1.w};        \
        short8 ah, am, al;                                                     \
        split3(xv, ah, am, al);                                                \
        acc0 = MFMA32(al, q0, acc0);                                           \
        acc0 = MFMA32(am, q1, acc0);                                           \
        acc0 = MFMA32(ah, q2, acc0);                                           \
        acc0 = MFMA32(am, q0, acc0);                                           \
        acc0 = MFMA32(ah, q1, acc0);                                           \
        acc0 = MFMA32(ah, q0, acc0);                                           \
        acc1 = MFMA32(al, q3, acc1);                                           \
        acc1 = MFMA32(am, q4, acc1);                                           \
        acc1 = MFMA32(ah, q5, acc1);                                           \
        acc1 = MFMA32(am, q3, acc1);                                           \
        acc1 = MFMA32(ah, q4, acc1);                                           \
        acc1 = MFMA32(ah, q3, acc1);                                           \
    } while (0)

    // prologue: fill both ping-pong buffers (FIFO: [wA xA wB xB] so each
    // phase's drain leaves the other phase's loads in flight)
    LOADW(wA0, wA1, wA2, wA3, wA4, wA5, 0); LOADX(xA0, xA1, 0);
    LOADW(wB0, wB1, wB2, wB3, wB4, wB5, 1); LOADX(xB0, xB1, 1);

    for (int t = 0; t < NK16; t += 2) {
        // phase A: first use drains wA/xA only; wB/xB + later loads stay in flight
        DOSTEP(xA0, xA1, wA0, wA1, wA2, wA3, wA4, wA5);
        {
            const int t2 = (t + 2) & (NK16 - 1);   // wrap: harmless reload at tail
            LOADW(wA0, wA1, wA2, wA3, wA4, wA5, t2); LOADX(xA0, xA1, t2);
        }
        // phase B (no sched_barrier: let the compiler interleave/soften waits)
        DOSTEP(xB0, xB1, wB0, wB1, wB2, wB3, wB4, wB5);
        {
            const int t3 = (t + 3) & (NK16 - 1);
            LOADW(wB0, wB1, wB2, wB3, wB4, wB5, t3); LOADX(xB0, xB1, t3);
        }
    }

    // ---- split-K partials to LDS (32x32 C layout) ----
#pragma unroll
    for (int reg = 0; reg < 16; ++reg) {
        const int rw = (reg & 3) + 8 * (reg >> 2) + 4 * h;
        part[wv][rw][e31]      = acc0[reg];
        part[wv][rw][32 + e31] = acc1[reg];
    }
    __syncthreads();

    float* out_vals = out;                          // [N][2]
    float* out_idx  = out + (size_t)N_ROWS * 2;     // [N][2] (as float)
    float* out_sc   = out + (size_t)N_ROWS * 4;     // [N][64]

    // wave wv finalizes rows wv*4 .. wv*4+3; lane = expert
#pragma unroll
    for (int i = 0; i < 4; ++i) {
        const int r = wv * 4 + i;
        const int row = row0 + r;
        float s = 0.f;
#pragma unroll
        for (int kw = 0; kw < KWAVES; ++kw) s += part[kw][r][lane];
        float m = s;
#pragma unroll
        for (int off = 32; off; off >>= 1) m = fmaxf(m, __shfl_xor(m, off));
        float e = expf(s - m);
        float sum = e;
#pragma unroll
        for (int off = 32; off; off >>= 1) sum += __shfl_xor(sum, off);
        float p = e / sum;
        out_sc[(size_t)row * 64 + lane] = p;

        // top-2 butterfly over 64 lanes (tie -> lowest index, matches lax.top_k)
        float v1 = p; int i1 = lane; float v2 = -1.f; int i2 = lane;
#pragma unroll
        for (int off = 32; off; off >>= 1) {
            float o1 = __shfl_xor(v1, off); int oi1 = __shfl_xor(i1, off);
            float o2 = __shfl_xor(v2, off); int oi2 = __shfl_xor(i2, off);
            if (gtpair(o1, oi1, v1, i1)) {
                if (gtpair(v1, i1, o2, oi2)) { v2 = v1; i2 = i1; }
                else                         { v2 = o2; i2 = oi2; }
                v1 = o1; i1 = oi1;
            } else if (gtpair(o1, oi1, v2, i2)) {
                v2 = o1; i2 = oi1;
            }
        }
        if (lane == 0) {
            out_vals[(size_t)row * 2 + 0] = v1;     // ROUTE_SCALE == 1.0
            out_vals[(size_t)row * 2 + 1] = v2;
            out_idx[(size_t)row * 2 + 0]  = (float)i1;
            out_idx[(size_t)row * 2 + 1]  = (float)i2;
        }
    }
}

extern "C" void kernel_launch(void* const* d_in, const int* in_sizes, int n_in,
                              void* d_out, int out_size, void* d_ws, size_t ws_size,
                              hipStream_t stream)
{
    const float* x = (const float*)d_in[0];
    const float* w = (const float*)d_in[1];
    float* out = (float*)d_out;

    short8* w0t = (short8*)d_ws;                    // 512 KB
    short8* w1t = w0t + (size_t)NSTEP * 2 * 64;     // 512 KB
    short8* w2t = w1t + (size_t)NSTEP * 2 * 64;     // 512 KB

    convw_kernel<<<dim3(128), dim3(256), 0, stream>>>(w, w0t, w1t, w2t);
    gate_kernel<<<dim3(N_ROWS / RPB), dim3(512), 0, stream>>>(x, w0t, w1t, w2t, out);
}

// Round 11
// 92.841 us; speedup vs baseline: 1.4077x; 1.4077x over previous
//
#include <hip/hip_runtime.h>
#include <math.h>

#define N_ROWS 16384
#define DIM 4096
#define NEXP 64
#define KWAVES 16
#define KSLICE (DIM / KWAVES)      // 256 k per wave
#define KC 32                      // k per chunk (one MFMA K-step)
#define NCHUNK (KSLICE / KC)       // 8
#define RPB 32                     // rows per block (2 M-tiles per wave)
#define NKO (DIM / 8)              // 512 k-octets

typedef short short8 __attribute__((ext_vector_type(8)));
typedef float f32x4  __attribute__((ext_vector_type(4)));

__device__ __forceinline__ unsigned cvt_pk_bf16(float a, float b) {
    unsigned r;
    asm("v_cvt_pk_bf16_f32 %0, %1, %2" : "=v"(r) : "v"(a), "v"(b));
    return r;   // low16 = bf16(a), high16 = bf16(b)
}

// 3-way split of 8 f32 into bf16 hi/mid/lo frags. Residual subtractions are
// exact, so x = h + m + l + eps with |eps| <= 2^-27 |x|.
__device__ __forceinline__ void split3(const float* xv, short8& h8, short8& m8, short8& l8) {
    union { unsigned u[4]; short8 s; } H, M, L;
#pragma unroll
    for (int j = 0; j < 4; ++j) {
        float a = xv[2 * j], b = xv[2 * j + 1];
        unsigned hp = cvt_pk_bf16(a, b);
        float a1 = a - __uint_as_float(hp << 16);
        float b1 = b - __uint_as_float(hp & 0xffff0000u);
        unsigned mp = cvt_pk_bf16(a1, b1);
        float a2 = a1 - __uint_as_float(mp << 16);
        float b2 = b1 - __uint_as_float(mp & 0xffff0000u);
        H.u[j] = hp; M.u[j] = mp; L.u[j] = cvt_pk_bf16(a2, b2);
    }
    h8 = H.s; m8 = M.s; l8 = L.s;
}

__device__ __forceinline__ bool gtpair(float a, int ia, float b, int ib) {
    return (a > b) || (a == b && ia < ib);
}

// ---- pre-kernel: W[64][4096] f32 -> three bf16 tables [ko][e] (k-octet packed) ----
__global__ __launch_bounds__(256)
void convw_kernel(const float* __restrict__ w, short8* __restrict__ w0t,
                  short8* __restrict__ w1t, short8* __restrict__ w2t)
{
    const int t  = blockIdx.x * 256 + threadIdx.x;   // 32768 = 512 ko x 64 e
    const int ko = t >> 6;
    const int e  = t & 63;
    const float* src = w + (size_t)e * DIM + ko * 8;
    float xv[8];
#pragma unroll
    for (int j = 0; j < 8; ++j) xv[j] = src[j];
    short8 h, m, l;
    split3(xv, h, m, l);
    w0t[ko * 64 + e] = h;
    w1t[ko * 64 + e] = m;
    w2t[ko * 64 + e] = l;
}

// ---- main: 512 blocks x 16 waves; wave wv covers k-slice wv*256..+256 for the
// block's 32 rows (2 M-tiles of 16). A-frag: row = lane&15, k-octet g = lane>>4
// (A/B share the k-order => any consistent order is valid). C-frag
// (m89-verified): col = lane&15, row = (lane>>4)*4 + reg.
// Load discipline per chunk: ALL 12 W loads issued first (oldest in vm FIFO),
// then the 4 x-prefetch loads (drained only next chunk) -> first-MFMA waitcnt
// covers only L2 latency, never the fresh HBM x loads.
__global__ __launch_bounds__(1024, 4)
void gate_kernel(const float* __restrict__ x, const short8* __restrict__ w0t,
                 const short8* __restrict__ w1t, const short8* __restrict__ w2t,
                 float* __restrict__ out)
{
    __shared__ float part[8][RPB][NEXP];        // 64 KB (two k-slices share a region)

    const int tid  = threadIdx.x;
    const int lane = tid & 63;
    const int wv   = tid >> 6;                  // 0..15 = k-slice
    const int l15  = lane & 15;
    const int g    = lane >> 4;
    const int row0 = blockIdx.x * RPB;

    f32x4 acc[2][4];
#pragma unroll
    for (int mt = 0; mt < 2; ++mt)
#pragma unroll
        for (int nt = 0; nt < 4; ++nt) acc[mt][nt] = (f32x4){0.f, 0.f, 0.f, 0.f};

    const float* xp0 = x + (size_t)(row0 + l15) * DIM + wv * KSLICE + g * 8;
    const float* xp1 = xp0 + 16 * DIM;

    float4 c00 = *reinterpret_cast<const float4*>(xp0);
    float4 c01 = *reinterpret_cast<const float4*>(xp0 + 4);
    float4 c10 = *reinterpret_cast<const float4*>(xp1);
    float4 c11 = *reinterpret_cast<const float4*>(xp1 + 4);

    for (int t = 0; t < NCHUNK; ++t) {
        // --- 1) all W loads for THIS chunk (L2-resident tables) ---
        const int base = (wv * 32 + t * 4 + g) * 64 + l15;
        short8 b0[4], b1[4], b2[4];
#pragma unroll
        for (int nt = 0; nt < 4; ++nt) {
            b0[nt] = w0t[base + nt * 16];
            b1[nt] = w1t[base + nt * 16];
            b2[nt] = w2t[base + nt * 16];
        }
        // --- 2) x prefetch for NEXT chunk (clamped on last iter) ---
        const int tn = (t < NCHUNK - 1 ? t + 1 : t) * KC;
        float4 n00 = *reinterpret_cast<const float4*>(xp0 + tn);
        float4 n01 = *reinterpret_cast<const float4*>(xp0 + tn + 4);
        float4 n10 = *reinterpret_cast<const float4*>(xp1 + tn);
        float4 n11 = *reinterpret_cast<const float4*>(xp1 + tn + 4);

        // --- 3) split current x (registers loaded LAST chunk, already resident) ---
        float v0[8] = {c00.x, c00.y, c00.z, c00.w, c01.x, c01.y, c01.z, c01.w};
        float v1[8] = {c10.x, c10.y, c10.z, c10.w, c11.x, c11.y, c11.z, c11.w};
        short8 a0h, a0m, a0l, a1h, a1m, a1l;
        split3(v0, a0h, a0m, a0l);
        split3(v1, a1h, a1m, a1l);

        // --- 4) MFMAs ---
#pragma unroll
        for (int nt = 0; nt < 4; ++nt) {
            acc[0][nt] = __builtin_amdgcn_mfma_f32_16x16x32_bf16(a0l, b0[nt], acc[0][nt], 0, 0, 0);
            acc[0][nt] = __builtin_amdgcn_mfma_f32_16x16x32_bf16(a0m, b1[nt], acc[0][nt], 0, 0, 0);
            acc[0][nt] = __builtin_amdgcn_mfma_f32_16x16x32_bf16(a0h, b2[nt], acc[0][nt], 0, 0, 0);
            acc[0][nt] = __builtin_amdgcn_mfma_f32_16x16x32_bf16(a0m, b0[nt], acc[0][nt], 0, 0, 0);
            acc[0][nt] = __builtin_amdgcn_mfma_f32_16x16x32_bf16(a0h, b1[nt], acc[0][nt], 0, 0, 0);
            acc[0][nt] = __builtin_amdgcn_mfma_f32_16x16x32_bf16(a0h, b0[nt], acc[0][nt], 0, 0, 0);

            acc[1][nt] = __builtin_amdgcn_mfma_f32_16x16x32_bf16(a1l, b0[nt], acc[1][nt], 0, 0, 0);
            acc[1][nt] = __builtin_amdgcn_mfma_f32_16x16x32_bf16(a1m, b1[nt], acc[1][nt], 0, 0, 0);
            acc[1][nt] = __builtin_amdgcn_mfma_f32_16x16x32_bf16(a1h, b2[nt], acc[1][nt], 0, 0, 0);
            acc[1][nt] = __builtin_amdgcn_mfma_f32_16x16x32_bf16(a1m, b0[nt], acc[1][nt], 0, 0, 0);
            acc[1][nt] = __builtin_amdgcn_mfma_f32_16x16x32_bf16(a1h, b1[nt], acc[1][nt], 0, 0, 0);
            acc[1][nt] = __builtin_amdgcn_mfma_f32_16x16x32_bf16(a1h, b0[nt], acc[1][nt], 0, 0, 0);
        }
        c00 = n00; c01 = n01; c10 = n10; c11 = n11;
    }

    // ---- two-phase split-K combine into 8 regions (column XOR-swizzled) ----
    // phase A: waves 8..15 write region wv-8; phase B: waves 0..7 add into region wv.
    if (wv >= 8) {
#pragma unroll
        for (int mt = 0; mt < 2; ++mt)
#pragma unroll
            for (int nt = 0; nt < 4; ++nt)
#pragma unroll
                for (int r = 0; r < 4; ++r) {
                    const int rw = mt * 16 + g * 4 + r;
                    const int cl = (nt * 16 + l15) ^ (((rw >> 2) & 3) << 4);
                    part[wv - 8][rw][cl] = acc[mt][nt][r];
                }
    }
    __syncthreads();
    if (wv < 8) {
#pragma unroll
        for (int mt = 0; mt < 2; ++mt)
#pragma unroll
            for (int nt = 0; nt < 4; ++nt)
#pragma unroll
                for (int r = 0; r < 4; ++r) {
                    const int rw = mt * 16 + g * 4 + r;
                    const int cl = (nt * 16 + l15) ^ (((rw >> 2) & 3) << 4);
                    part[wv][rw][cl] += acc[mt][nt][r];
                }
    }
    __syncthreads();

    float* out_vals = out;                          // [N][2]
    float* out_idx  = out + (size_t)N_ROWS * 2;     // [N][2] (as float)
    float* out_sc   = out + (size_t)N_ROWS * 4;     // [N][64]

    // wave wv finalizes rows wv*2 .. wv*2+1; lane = expert
#pragma unroll
    for (int i = 0; i < 2; ++i) {
        const int r = wv * 2 + i;
        const int row = row0 + r;
        const int cl = lane ^ (((r >> 2) & 3) << 4);
        float s = 0.f;
#pragma unroll
        for (int kw = 0; kw < 8; ++kw) s += part[kw][r][cl];
        float m = s;
#pragma unroll
        for (int off = 32; off; off >>= 1) m = fmaxf(m, __shfl_xor(m, off));
        float e = expf(s - m);
        float sum = e;
#pragma unroll
        for (int off = 32; off; off >>= 1) sum += __shfl_xor(sum, off);
        float p = e / sum;
        out_sc[(size_t)row * 64 + lane] = p;

        // top-2 butterfly over 64 lanes (tie -> lowest index, matches lax.top_k)
        float v1 = p; int i1 = lane; float v2 = -1.f; int i2 = lane;
#pragma unroll
        for (int off = 32; off; off >>= 1) {
            float o1 = __shfl_xor(v1, off); int oi1 = __shfl_xor(i1, off);
            float o2 = __shfl_xor(v2, off); int oi2 = __shfl_xor(i2, off);
            if (gtpair(o1, oi1, v1, i1)) {
                if (gtpair(v1, i1, o2, oi2)) { v2 = v1; i2 = i1; }
                else                         { v2 = o2; i2 = oi2; }
                v1 = o1; i1 = oi1;
            } else if (gtpair(o1, oi1, v2, i2)) {
                v2 = o1; i2 = oi1;
            }
        }
        if (lane == 0) {
            out_vals[(size_t)row * 2 + 0] = v1;     // ROUTE_SCALE == 1.0
            out_vals[(size_t)row * 2 + 1] = v2;
            out_idx[(size_t)row * 2 + 0]  = (float)i1;
            out_idx[(size_t)row * 2 + 1]  = (float)i2;
        }
    }
}

extern "C" void kernel_launch(void* const* d_in, const int* in_sizes, int n_in,
                              void* d_out, int out_size, void* d_ws, size_t ws_size,
                              hipStream_t stream)
{
    const float* x = (const float*)d_in[0];
    const float* w = (const float*)d_in[1];
    float* out = (float*)d_out;

    short8* w0t = (short8*)d_ws;            // 512 KB
    short8* w1t = w0t + NKO * NEXP;         // 512 KB
    short8* w2t = w1t + NKO * NEXP;         // 512 KB

    convw_kernel<<<dim3(128), dim3(256), 0, stream>>>(w, w0t, w1t, w2t);
    gate_kernel<<<dim3(N_ROWS / RPB), dim3(1024), 0, stream>>>(x, w0t, w1t, w2t, out);
}